// Round 8
// baseline (304.172 us; speedup 1.0000x reference)
//
#include <hip/hip_runtime.h>
#include <cstdint>
#include <cstddef>

typedef int int32x4  __attribute__((ext_vector_type(4)));
typedef int int32x16 __attribute__((ext_vector_type(16)));

// ---------------------------------------------------------------------------
// Kernel 1: x (fp32, int8-valued) -> A8 (int8, row-major) + row sums rs.
// ---------------------------------------------------------------------------
__global__ __launch_bounds__(256) void quant_x(const float* __restrict__ x,
                                               signed char* __restrict__ A8,
                                               int* __restrict__ rs) {
    const int row = blockIdx.x;
    const int t = threadIdx.x;
    const float4* xr = (const float4*)(x + (size_t)row * 4096);
    char4* ar = (char4*)(A8 + (size_t)row * 4096);
    int s = 0;
#pragma unroll
    for (int i = 0; i < 4; i++) {
        const int idx = i * 256 + t;
        float4 v = xr[idx];
        int a0 = (int)v.x, a1 = (int)v.y, a2 = (int)v.z, a3 = (int)v.w;
        s += a0 + a1 + a2 + a3;
        char4 c;
        c.x = (signed char)a0; c.y = (signed char)a1;
        c.z = (signed char)a2; c.w = (signed char)a3;
        ar[idx] = c;
    }
#pragma unroll
    for (int off = 32; off > 0; off >>= 1) s += __shfl_down(s, off);
    __shared__ int wsum[4];
    if ((t & 63) == 0) wsum[t >> 6] = s;
    __syncthreads();
    if (t == 0) rs[row] = wsum[0] + wsum[1] + wsum[2] + wsum[3];
}

// ---------------------------------------------------------------------------
// Kernel 2: y (fp32, uint8-valued) -> Bpk: MFMA-fragment-linear packed int8
// (y-128), + col sums sy (fused; sy pre-zeroed by memset).
// Pack: element (n,k) -> offset ((n>>5)*128 + (k>>5))*1024
//                        + ((n&31) + 32*((k>>4)&1))*16 + (k&15).
// (validated rounds 7: absmax 32)
// ---------------------------------------------------------------------------
__global__ __launch_bounds__(256) void quant_y(const float* __restrict__ y,
                                               signed char* __restrict__ Bpk,
                                               int* __restrict__ sy) {
    __shared__ __align__(16) signed char tile[64 * 68];  // tile[n*68 + k]
    __shared__ int ssum[64];
    const int nt = blockIdx.x * 64;
    const int kt = blockIdx.y * 64;
    const int t = threadIdx.x;
    if (t < 64) ssum[t] = 0;
    __syncthreads();

    const int r0 = t >> 4;
    const int c4 = (t & 15) * 4;
    int s0 = 0, s1 = 0, s2 = 0, s3 = 0;
#pragma unroll
    for (int i = 0; i < 4; i++) {
        const int k = i * 16 + r0;
        float4 v = *(const float4*)(y + (size_t)(kt + k) * 4096 + nt + c4);
        int b0 = (int)v.x - 128, b1 = (int)v.y - 128;
        int b2 = (int)v.z - 128, b3 = (int)v.w - 128;
        s0 += b0; s1 += b1; s2 += b2; s3 += b3;
        tile[(c4 + 0) * 68 + k] = (signed char)b0;
        tile[(c4 + 1) * 68 + k] = (signed char)b1;
        tile[(c4 + 2) * 68 + k] = (signed char)b2;
        tile[(c4 + 3) * 68 + k] = (signed char)b3;
    }
    atomicAdd(&ssum[c4 + 0], s0);
    atomicAdd(&ssum[c4 + 1], s1);
    atomicAdd(&ssum[c4 + 2], s2);
    atomicAdd(&ssum[c4 + 3], s3);
    __syncthreads();

    const int q  = t & 127;
    const int rh = t >> 7;
    const int k32sel = q >> 6;
    const int lq = q & 63;
    const int n_loc = rh * 32 + (lq & 31);
    const int k_loc = k32sel * 32 + (lq >> 5) * 16;
    const signed char* src = tile + n_loc * 68 + k_loc;
    int32x4 w;
    w.x = *(const int*)(src + 0);
    w.y = *(const int*)(src + 4);
    w.z = *(const int*)(src + 8);
    w.w = *(const int*)(src + 12);
    const size_t dst = ((size_t)((nt >> 5) + rh) * 128 + (kt >> 5) + k32sel) * 1024 + lq * 16;
    *(int32x4*)(Bpk + dst) = w;
    if (t < 64) atomicAdd(&sy[nt + t], ssum[t]);
}

// ---------------------------------------------------------------------------
// Kernel 3: int8 GEMM, NO global_load_lds (rounds 1-7 showed the LDS-DMA
// path saturates at ~16 B/cyc/CU -- the invariant ~3500-cyc iteration).
// Staging: global->VGPR (reg double-buffer, depth-1) -> ds_write_b128 ->
// raw s_barrier with lgkmcnt(0) only (no vmcnt drain: next tile's global
// loads stay in flight across the barrier).
// Block 256(M) x 128(N), BK=64, 4 waves 2x2, wave tile 128x64 = 4x2 grid
// of 32x32x32 i8 MFMAs. LDS holds A and B FRAGMENT-LINEAR (ds_write can
// scatter, unlike the DMA): chunk(m32,k32) = 1KB, granule = lane*16.
// A-writes XOR lane with 2*k32 (2-way banks = free); reads XOR back.
// B-writes/reads pure lane-linear (conflict-free).
// Epilogue: C = 7.5e-4 * (P - 32*rs[m] + 66*sy[n] - 8650752)
// ---------------------------------------------------------------------------
__global__ __launch_bounds__(256, 2) void gemm_i8(const signed char* __restrict__ A8,
                                                  const signed char* __restrict__ Bpk,
                                                  const int* __restrict__ rs,
                                                  const int* __restrict__ sy,
                                                  float* __restrict__ C) {
    __shared__ __align__(16) signed char As[2][16384];  // 16 chunks x 1KB, dbuf
    __shared__ __align__(16) signed char Bs[2][8192];   // 8 chunks x 1KB, dbuf
    const int tid = threadIdx.x;
    const int bm = blockIdx.y * 256;
    const int bn = blockIdx.x * 128;
    const int lane = tid & 63;
    const int wave = tid >> 6;
    const int wm32 = (wave >> 1) * 4;   // A chunk-row base (m32 units)
    const int wnc  = (wave & 1) * 2;    // B chunk base (n32loc units)
    const int mr = lane & 31;
    const int kh = lane >> 5;
    const int bn32 = bn >> 5;

    int32x16 acc[4][2] = {};

    // ---- A global source: thread t -> rows 64p + (t>>2), 16B chunk t&3
    const signed char* a_src = A8 + (size_t)(bm + (tid >> 2)) * 4096 + (tid & 3) * 16;
    // ---- A LDS write offsets (fragment-linear + XOR(2*k32) on lane):
    // element home: chunk = (row>>5)*2 + k32, l16 = (row&31) + 32*half
    int a_woff[4];
    {
        const int k32 = (tid & 3) >> 1;
        const int half = tid & 1;
        const int l16 = ((tid >> 2) & 31) + 32 * half;
        const int pl = (l16 ^ (2 * k32)) * 16;
#pragma unroll
        for (int p = 0; p < 4; p++)
            a_woff[p] = ((2 * p + (tid >> 7)) * 2 + k32) * 1024 + pl;
    }
    // ---- B: thread t covers LDS chunks c = (t>>6) and 4 + (t>>6)
    const int bc0 = tid >> 6;

    auto loadA = [&](int32x4 (&ar)[4], int kt) {
#pragma unroll
        for (int p = 0; p < 4; p++)
            ar[p] = *(const int32x4*)(a_src + (size_t)(64 * p) * 4096 + kt);
    };
    auto loadB = [&](int32x4 (&br)[2], int kt) {
        const int kt32 = kt >> 5;
#pragma unroll
        for (int q = 0; q < 2; q++) {
            const int c = bc0 + 4 * q;
            br[q] = *(const int32x4*)(Bpk +
                ((size_t)(bn32 + (c >> 1)) * 128 + kt32 + (c & 1)) * 1024 + lane * 16);
        }
    };
    auto writeLDS = [&](int buf, int32x4 (&ar)[4], int32x4 (&br)[2]) {
#pragma unroll
        for (int p = 0; p < 4; p++)
            *(int32x4*)(&As[buf][a_woff[p]]) = ar[p];
        *(int32x4*)(&Bs[buf][tid * 16]) = br[0];
        *(int32x4*)(&Bs[buf][tid * 16 + 4096]) = br[1];
    };
    auto compute = [&](int buf) {
#pragma unroll
        for (int ks = 0; ks < 2; ks++) {
            int32x4 af[4], bf[2];
            const int alane = (lane ^ (2 * ks)) * 16;
#pragma unroll
            for (int m = 0; m < 4; m++)
                af[m] = *(const int32x4*)(&As[buf][((wm32 + m) * 2 + ks) * 1024 + alane]);
#pragma unroll
            for (int nj = 0; nj < 2; nj++)
                bf[nj] = *(const int32x4*)(&Bs[buf][((wnc + nj) * 2 + ks) * 1024 + lane * 16]);
#pragma unroll
            for (int m = 0; m < 4; m++)
#pragma unroll
                for (int nj = 0; nj < 2; nj++)
                    acc[m][nj] = __builtin_amdgcn_mfma_i32_32x32x32_i8(af[m], bf[nj], acc[m][nj], 0, 0, 0);
        }
    };

    int32x4 areg[2][4];
    int32x4 breg[2][2];
    loadA(areg[0], 0);
    loadB(breg[0], 0);

#pragma unroll 1
    for (int i = 0; i < 64; i++) {
        const int kt_next = ((i + 1) << 6) & 4095;   // clamp: const load count
        loadA(areg[(i + 1) & 1], kt_next);
        loadB(breg[(i + 1) & 1], kt_next);
        __builtin_amdgcn_sched_barrier(0);
        __builtin_amdgcn_s_waitcnt(0x0F76);          // vmcnt(6): set i landed
        __builtin_amdgcn_sched_barrier(0);
        writeLDS(i & 1, areg[i & 1], breg[i & 1]);
        __builtin_amdgcn_sched_barrier(0);
        __builtin_amdgcn_s_waitcnt(0xC07F);          // lgkmcnt(0) only (~30cyc)
        __builtin_amdgcn_s_barrier();                // raw: no vmcnt drain
        __builtin_amdgcn_sched_barrier(0);
        compute(i & 1);
    }

    // Epilogue. C/D: col = lane&31, row = (reg&3) + 8*(reg>>2) + 4*kh
#pragma unroll
    for (int i = 0; i < 4; i++) {
#pragma unroll
        for (int r = 0; r < 16; r++) {
            const int gm = bm + (wave >> 1) * 128 + i * 32 + (r & 3) + 8 * (r >> 2) + 4 * kh;
            const int rcorr = -32 * rs[gm] - 8650752;
#pragma unroll
            for (int j = 0; j < 2; j++) {
                const int gn = bn + (wave & 1) * 64 + j * 32 + mr;
                const int v = acc[i][j][r] + rcorr + 66 * sy[gn];
                C[(size_t)gm * 4096 + gn] = 7.5e-4f * (float)v;
            }
        }
    }
}

// ---------------------------------------------------------------------------
extern "C" void kernel_launch(void* const* d_in, const int* in_sizes, int n_in,
                              void* d_out, int out_size, void* d_ws, size_t ws_size,
                              hipStream_t stream) {
    const float* x = (const float*)d_in[0];  // [4096,4096] int8-valued
    const float* y = (const float*)d_in[1];  // [4096,4096] uint8-valued
    float* out = (float*)d_out;

    char* ws = (char*)d_ws;
    signed char* A8  = (signed char*)ws;                         // 16 MiB
    signed char* Bpk = (signed char*)(ws + (16u << 20));         // 16 MiB packed
    int* rs = (int*)(ws + (32u << 20));                          // 16 KiB
    int* sy = (int*)(ws + (32u << 20) + (16u << 10));            // 16 KiB

    hipMemsetAsync(sy, 0, 4096 * sizeof(int), stream);
    quant_x<<<4096, 256, 0, stream>>>(x, A8, rs);
    quant_y<<<dim3(64, 64), 256, 0, stream>>>(y, Bpk, sy);
    gemm_i8<<<dim3(32, 16), 256, 0, stream>>>(A8, Bpk, rs, sy, out);
}